// Round 16
// baseline (437.711 us; speedup 1.0000x reference)
//
#include <hip/hip_runtime.h>

#define N_NODES 100000
#define N_EDGES 1600000
#define NBKT 391          // ceil(100000/256) buckets of 256 nodes
#define BKT_CAP 4608      // padded bucket capacity (avg 4092, +8 sigma)
#define NCHUNK 782        // edge chunks
#define CHUNK_E 2048
#define GEMM_GRID 522

typedef _Float16 half8 __attribute__((ext_vector_type(8)));
typedef float floatx4 __attribute__((ext_vector_type(4)));

// ================= deterministic CSR build =================

__global__ __launch_bounds__(256) void k_count(const int* __restrict__ ei,
                                               unsigned* __restrict__ Mcnt) {
    __shared__ unsigned hist[NBKT];
    int tid = threadIdx.x;
    int e0 = blockIdx.x * CHUNK_E + tid * 8;
    for (int i = tid; i < NBKT; i += 256) hist[i] = 0;
    __syncthreads();
    if (e0 + 8 <= N_EDGES) {
        #pragma unroll
        for (int v = 0; v < 2; v++) {
            int4 c = *(const int4*)(ei + N_EDGES + e0 + v * 4);
            atomicAdd(&hist[(unsigned)c.x >> 8], 1u);
            atomicAdd(&hist[(unsigned)c.y >> 8], 1u);
            atomicAdd(&hist[(unsigned)c.z >> 8], 1u);
            atomicAdd(&hist[(unsigned)c.w >> 8], 1u);
        }
    } else {
        for (int i = 0; i < 8; i++) {
            if (e0 + i < N_EDGES)
                atomicAdd(&hist[(unsigned)ei[N_EDGES + e0 + i] >> 8], 1u);
        }
    }
    __syncthreads();
    for (int i = tid; i < NBKT; i += 256) Mcnt[i * NCHUNK + blockIdx.x] = hist[i];
}

__global__ __launch_bounds__(256) void k_base(const unsigned* __restrict__ Mcnt,
                                              unsigned* __restrict__ Mbase,
                                              unsigned* __restrict__ btot) {
    __shared__ unsigned s[256];
    int t = threadIdx.x;
    int j = blockIdx.x;
    const unsigned* src = Mcnt + (size_t)j * NCHUNK;
    unsigned* dst = Mbase + (size_t)j * NCHUNK;
    unsigned carry = 0;
    for (int seg = 0; seg < NCHUNK; seg += 256) {
        int idx = seg + t;
        unsigned v = (idx < NCHUNK) ? src[idx] : 0u;
        s[t] = v;
        __syncthreads();
        for (int d = 1; d < 256; d <<= 1) {
            unsigned u = (t >= d) ? s[t - d] : 0u;
            __syncthreads();
            s[t] += u;
            __syncthreads();
        }
        if (idx < NCHUNK) dst[idx] = s[t] - v + carry;
        carry += s[255];
        __syncthreads();
    }
    if (t == 0) btot[j] = carry;
}

// k_place: one wave per chunk; stable deterministic scatter via ballot ranks.
// payload u64 = [ew f32 bits : 63..32 | cl : 24..17 | row : 16..0]

__global__ __launch_bounds__(64) void k_place(const int* __restrict__ ei,
                                              const float* __restrict__ ew,
                                              const unsigned* __restrict__ Mbase,
                                              unsigned long long* __restrict__ part) {
    __shared__ unsigned lrank[NBKT];
    int lane = threadIdx.x;
    int p = blockIdx.x;
    int e0 = p * CHUNK_E;
    int nloc = N_EDGES - e0; if (nloc > CHUNK_E) nloc = CHUNK_E;
    for (int i = lane; i < NBKT; i += 64) lrank[i] = Mbase[i * NCHUNK + p];
    __syncthreads();
    for (int it = 0; it < CHUNK_E; it += 64) {
        if (it >= nloc) break;
        int li = it + lane;
        bool valid = li < nloc;
        unsigned col = 0, row = 0; float wv = 0.f;
        if (valid) {
            col = (unsigned)ei[N_EDGES + e0 + li];
            row = (unsigned)ei[e0 + li];
            wv = ew[e0 + li];
        }
        unsigned bk = col >> 8;
        unsigned long long m = __ballot(valid ? 1 : 0);
        #pragma unroll
        for (int b = 0; b < 9; b++) {
            unsigned long long bal = __ballot((bk >> b) & 1u);
            m &= ((bk >> b) & 1u) ? bal : ~bal;
        }
        unsigned rank = (unsigned)__popcll(m & ((1ull << lane) - 1ull));
        unsigned cntk = (unsigned)__popcll(m);
        unsigned base = lrank[bk];
        if (valid) {
            unsigned u; __builtin_memcpy(&u, &wv, 4);
            unsigned long long pay = ((unsigned long long)u << 32)
                                   | (((unsigned long long)(col & 255u)) << 17)
                                   | (unsigned long long)row;
            part[(size_t)bk * BKT_CAP + base + rank] = pay;
        }
        bool leader = valid && (lane == (__ffsll((long long)m) - 1));
        if (leader) lrank[bk] = base + cntk;
        __syncthreads();
    }
}

__global__ __launch_bounds__(64) void k_colsort(const unsigned* __restrict__ btot,
                                                const unsigned long long* __restrict__ part,
                                                unsigned long long* __restrict__ sorted,
                                                float* __restrict__ dis,
                                                int* __restrict__ offs,
                                                int* __restrict__ cnt) {
    __shared__ unsigned long long sh[BKT_CAP];
    __shared__ unsigned hist[256];
    __shared__ unsigned cbase[256];
    __shared__ unsigned cur[256];
    int lane = threadIdx.x;
    int j = blockIdx.x;
    int count = (int)btot[j];
    size_t p0 = (size_t)j * BKT_CAP;
    for (int i = lane; i < 256; i += 64) hist[i] = 0;
    __syncthreads();
    for (int i = lane; i < count; i += 64) {
        unsigned cl = (unsigned)(part[p0 + i] >> 17) & 255u;
        atomicAdd(&hist[cl], 1u);
    }
    __syncthreads();
    unsigned h0 = hist[lane * 4], h1 = hist[lane * 4 + 1];
    unsigned h2 = hist[lane * 4 + 2], h3 = hist[lane * 4 + 3];
    unsigned lsum = h0 + h1 + h2 + h3;
    unsigned inc = lsum;
    #pragma unroll
    for (int d = 1; d < 64; d <<= 1) {
        unsigned u = __shfl_up(inc, d, 64);
        if (lane >= d) inc += u;
    }
    unsigned lex = inc - lsum;
    cbase[lane * 4]     = lex;
    cbase[lane * 4 + 1] = lex + h0;
    cbase[lane * 4 + 2] = lex + h0 + h1;
    cbase[lane * 4 + 3] = lex + h0 + h1 + h2;
    __syncthreads();
    for (int i = lane; i < 256; i += 64) cur[i] = cbase[i];
    __syncthreads();
    for (int it = 0; it < count; it += 64) {
        int i = it + lane;
        bool valid = i < count;
        unsigned long long v = valid ? part[p0 + i] : 0ull;
        unsigned cl = (unsigned)(v >> 17) & 255u;
        unsigned long long m = __ballot(valid ? 1 : 0);
        #pragma unroll
        for (int b = 0; b < 8; b++) {
            unsigned long long bal = __ballot((cl >> b) & 1u);
            m &= ((cl >> b) & 1u) ? bal : ~bal;
        }
        unsigned rank = (unsigned)__popcll(m & ((1ull << lane) - 1ull));
        unsigned base = cur[cl];
        if (valid) sh[base + rank] = v;
        bool leader = valid && (lane == (__ffsll((long long)m) - 1));
        if (leader) cur[cl] = base + (unsigned)__popcll(m);
        __syncthreads();
    }
    for (int i = lane; i < count; i += 64) sorted[p0 + i] = sh[i];
    #pragma unroll
    for (int k = 0; k < 4; k++) {
        int c = lane * 4 + k;
        int col = j * 256 + c;
        if (col >= N_NODES) continue;
        unsigned n = hist[c];
        unsigned b = cbase[c];
        float deg = 0.f;
        for (unsigned i = 0; i < n; i++) {
            unsigned u = (unsigned)(sh[b + i] >> 32);
            float wv; __builtin_memcpy(&wv, &u, 4);
            deg += wv;
        }
        dis[col] = rsqrtf(deg + 1.0f);
        cnt[col] = (int)n;
        offs[col] = (int)(p0 + b);
    }
}

__global__ __launch_bounds__(256) void k_final(const unsigned long long* __restrict__ sorted,
                                               const float* __restrict__ dis,
                                               const int* __restrict__ offs,
                                               const int* __restrict__ cnt,
                                               unsigned* __restrict__ csr,
                                               float* __restrict__ svec) {
    int col = blockIdx.x * 256 + threadIdx.x;
    if (col >= N_NODES) return;
    int n = cnt[col];
    int o = offs[col];
    float dc = dis[col];
    float ssum = 0.f;
    for (int i = 0; i < n; i++) {
        unsigned long long v = sorted[(size_t)o + i];
        unsigned u = (unsigned)(v >> 32);
        float wv; __builtin_memcpy(&wv, &u, 4);
        unsigned row = (unsigned)(v & 0x1FFFFu);
        float w = dis[row] * wv * dc;
        _Float16 hw = (_Float16)w;
        unsigned short hb; __builtin_memcpy(&hb, &hw, 2);
        csr[(size_t)o + i] = ((unsigned)hb << 17) | row;
        ssum += (float)hw;
    }
    svec[col] = ssum + dc * dc;
}

// ================= weight prep =================

__global__ __launch_bounds__(256) void prep_mm(const float* __restrict__ W2,
                                               const float* __restrict__ c1W,
                                               _Float16* __restrict__ Wt0) {
    __shared__ float sW[128 * 128];
    int t = threadIdx.x;
    for (int i = t; i < 4096; i += 256) ((float4*)sW)[i] = ((const float4*)c1W)[i];
    __syncthreads();
    int k = blockIdx.x * 2 + (t >> 7);
    int col = t & 127;
    float acc = 0.f;
    #pragma unroll 8
    for (int j = 0; j < 128; j++) acc = fmaf(W2[k * 128 + j], sW[j * 128 + col], acc);
    Wt0[col * 128 + k] = (_Float16)acc;
}

__global__ __launch_bounds__(128) void prep_bb(const float* __restrict__ b2,
                                               const float* __restrict__ c1W,
                                               float* __restrict__ bb) {
    int c = threadIdx.x;
    float acc = 0.f;
    for (int j = 0; j < 128; j++) acc = fmaf(b2[j], c1W[j * 128 + c], acc);
    bb[c] = acc;
}

__global__ __launch_bounds__(256) void prep_tr(const float* __restrict__ Wa,
                                               const float* __restrict__ Wb,
                                               _Float16* __restrict__ Wt) {
    int m = blockIdx.x >> 4;
    const float* W = (m == 0) ? Wa : Wb;
    _Float16* o = Wt + (m + 1) * 16384;
    int base = (blockIdx.x & 15) * 1024 + threadIdx.x * 4;
    int col = base >> 7;
    int k0 = base & 127;
    #pragma unroll
    for (int i = 0; i < 4; i++) o[base + i] = (_Float16)W[(k0 + i) * 128 + col];
}

// ================= encoder layer 1 =================

__global__ __launch_bounds__(256) void enc1_kernel(const float* __restrict__ x,
                                                   const float* __restrict__ W1,
                                                   const float* __restrict__ b1,
                                                   _Float16* __restrict__ out) {
    __shared__ float sX[256 * 17];
    __shared__ float sW[2048];
    __shared__ float sb[128];
    int t = threadIdx.x;
    int base = blockIdx.x * 256;
    for (int i = t; i < 512; i += 256) ((float4*)sW)[i] = ((const float4*)W1)[i];
    if (t < 128) sb[t] = b1[t];
    #pragma unroll
    for (int i = 0; i < 4; i++) {
        int f = i * 1024 + t * 4;
        int row = f >> 4, k = f & 15;
        float4 v = make_float4(0.f, 0.f, 0.f, 0.f);
        if (base + row < N_NODES) v = *(const float4*)(x + (size_t)(base + row) * 16 + k);
        *(float4*)(sX + row * 17 + k) = v;
    }
    __syncthreads();
    int row = base + t;
    if (row >= N_NODES) return;
    float xr[16];
    #pragma unroll
    for (int k = 0; k < 16; k++) xr[k] = sX[t * 17 + k];
    #pragma unroll 4
    for (int cb = 0; cb < 16; cb++) {
        float acc[8];
        #pragma unroll
        for (int jj = 0; jj < 8; jj++) acc[jj] = sb[cb * 8 + jj];
        #pragma unroll
        for (int k = 0; k < 16; k++) {
            float xv = xr[k];
            #pragma unroll
            for (int jj = 0; jj < 8; jj++) acc[jj] = fmaf(xv, sW[k * 128 + cb * 8 + jj], acc[jj]);
        }
        half8 h;
        #pragma unroll
        for (int jj = 0; jj < 8; jj++) h[jj] = (_Float16)fmaxf(acc[jj], 0.f);
        *(half8*)(out + (size_t)row * 128 + cb * 8) = h;
    }
}

// ================= f16 MFMA GEMM (2-phase pipelined, race-fixed barriers) =================
// Cross-wave LDS visibility: every pre-barrier wait now drains lgkmcnt(0) so
// sE/sW2 ds_writes are visible after the barrier; vmcnt stays counted (4) so
// the prefetch pipeline is preserved.

template <bool BIAS, bool RELU, bool DEC, bool SB>
__global__ __launch_bounds__(256, 2) void gemm_mfma(const _Float16* __restrict__ A,
                                                    const _Float16* __restrict__ Wt,
                                                    const float* __restrict__ bias,
                                                    _Float16* __restrict__ C,
                                                    const float* __restrict__ W2,
                                                    const float* __restrict__ b2,
                                                    float* __restrict__ sm_out,
                                                    const float* __restrict__ svec,
                                                    const float* __restrict__ bbv) {
    __shared__ _Float16 sA[2 * 64 * 128];
    __shared__ _Float16 sE[DEC ? 64 : 64 * 128];
    __shared__ float sW2[DEC ? 256 : 1];
    int t = threadIdx.x;
    int lane = t & 63;
    int w = t >> 6;
    int l15 = lane & 15;
    int l4 = lane >> 4;

    half8 bfrag[8][4];
    #pragma unroll
    for (int n = 0; n < 8; n++)
        #pragma unroll
        for (int kk = 0; kk < 4; kk++)
            bfrag[n][kk] = *(const half8*)(Wt + (n * 16 + l15) * 128 + kk * 32 + l4 * 8);

    float bcol[8];
    if constexpr (BIAS) {
        #pragma unroll
        for (int n = 0; n < 8; n++) bcol[n] = bias[n * 16 + l15];
    }
    float bbcol[8];
    if constexpr (SB) {
        #pragma unroll
        for (int n = 0; n < 8; n++) bbcol[n] = bbv[n * 16 + l15];
    }
    float b20 = 0.f, b21 = 0.f;
    if constexpr (DEC) {
        if (t < 256) sW2[t] = W2[t];
        b20 = b2[0]; b21 = b2[1];
    }

    auto STAGE = [&](int buf, int tile) {
        const _Float16* Ag = A + (size_t)tile * 64 * 128;
        #pragma unroll
        for (int i = 0; i < 4; i++) {
            int c = i * 256 + t;
            int row = c >> 4;
            int g = (c & 15) ^ (row & 7);
            const _Float16* src = Ag + row * 128 + g * 8;
            __builtin_amdgcn_global_load_lds(
                (const __attribute__((address_space(1))) void*)src,
                (__attribute__((address_space(3))) void*)(sA + buf * 8192 + (size_t)(i * 256 + w * 64) * 8),
                16, 0, 0);
        }
    };

    const int NT = (N_NODES + 63) / 64;
    int cur = 0;
    STAGE(0, blockIdx.x);

    for (int tile = blockIdx.x; tile < NT; tile += GEMM_GRID) {
        int nx = tile + GEMM_GRID;
        if (nx < NT) {
            STAGE(cur ^ 1, nx);
            asm volatile("s_waitcnt vmcnt(4) lgkmcnt(0)" ::: "memory");
        } else {
            asm volatile("s_waitcnt vmcnt(0) lgkmcnt(0)" ::: "memory");
        }
        __builtin_amdgcn_s_barrier();
        asm volatile("" ::: "memory");

        const _Float16* sAc = sA + cur * 8192;

        floatx4 acc[8];
        #pragma unroll
        for (int n = 0; n < 8; n++) acc[n] = (floatx4)(0.f);

        #pragma unroll
        for (int kk = 0; kk < 4; kk++) {
            int rloc = w * 16 + l15;
            int cl = kk * 4 + l4;
            int s = cl ^ (rloc & 7);
            half8 af = *(const half8*)(sAc + rloc * 128 + s * 8);
            #pragma unroll
            for (int n = 0; n < 8; n++)
                acc[n] = __builtin_amdgcn_mfma_f32_16x16x32_f16(af, bfrag[n][kk], acc[n], 0, 0, 0);
        }

        size_t base_row = (size_t)tile * 64;
        float s4[4];
        if constexpr (SB) {
            #pragma unroll
            for (int r = 0; r < 4; r++) {
                int rr = (int)base_row + w * 16 + l4 * 4 + r;
                s4[r] = (rr < N_NODES) ? svec[rr] : 0.f;
            }
        }
        if constexpr (DEC) {
            #pragma unroll
            for (int r = 0; r < 4; r++) {
                float p0 = 0.f, p1 = 0.f;
                #pragma unroll
                for (int n = 0; n < 8; n++) {
                    float v = acc[n][r];
                    if constexpr (BIAS) v += bcol[n];
                    if constexpr (RELU) v = fmaxf(v, 0.f);
                    int ch = n * 16 + l15;
                    p0 = fmaf(v, sW2[ch * 2 + 0], p0);
                    p1 = fmaf(v, sW2[ch * 2 + 1], p1);
                }
                #pragma unroll
                for (int m = 1; m < 16; m <<= 1) {
                    p0 += __shfl_xor(p0, m, 64);
                    p1 += __shfl_xor(p1, m, 64);
                }
                size_t grow = base_row + w * 16 + l4 * 4 + r;
                if (l15 == 0 && grow < N_NODES) {
                    float z0 = p0 + b20, z1 = p1 + b21;
                    float mx = fmaxf(z0, z1);
                    float e0 = expf(z0 - mx), e1 = expf(z1 - mx);
                    float si = 1.f / (e0 + e1);
                    *(float2*)(sm_out + grow * 2) = make_float2(e0 * si, e1 * si);
                }
            }
            asm volatile("s_waitcnt lgkmcnt(0)" ::: "memory");
            __builtin_amdgcn_s_barrier();
            asm volatile("" ::: "memory");
        } else {
            #pragma unroll
            for (int n = 0; n < 8; n++) {
                #pragma unroll
                for (int r = 0; r < 4; r++) {
                    float v = acc[n][r];
                    if constexpr (SB) v += s4[r] * bbcol[n];
                    if constexpr (BIAS) v += bcol[n];
                    if constexpr (RELU) v = fmaxf(v, 0.f);
                    int row = w * 16 + l4 * 4 + r;
                    sE[row * 128 + n * 16 + l15] = (_Float16)v;
                }
            }
            asm volatile("s_waitcnt lgkmcnt(0)" ::: "memory");
            __builtin_amdgcn_s_barrier();
            asm volatile("" ::: "memory");
            #pragma unroll
            for (int i = 0; i < 4; i++) {
                int c = i * 256 + t;
                int row = c >> 4;
                if (base_row + row < N_NODES) {
                    *(float4*)((char*)C + (base_row + row) * 256 + (c & 15) * 16) =
                        *(const float4*)((const char*)sE + (size_t)c * 16);
                }
            }
        }
        cur ^= 1;
    }
}

// ================= GCN aggregation (masked 16-wide, deterministic) =================

__device__ __forceinline__ float wdec(unsigned u) {
    unsigned short b = (unsigned short)(u >> 17);
    _Float16 h;
    __builtin_memcpy(&h, &b, 2);
    return (float)h;
}

__global__ __launch_bounds__(256) void agg_kernel(const _Float16* __restrict__ m,
                                                  const int* __restrict__ offs,
                                                  const int* __restrict__ cnt,
                                                  const unsigned* __restrict__ csr,
                                                  const float* __restrict__ dis,
                                                  _Float16* __restrict__ out) {
    int wave = threadIdx.x >> 6;
    int lane = threadIdx.x & 63;
    int g = lane >> 4;
    int q = lane & 15;
    int j = blockIdx.x * 4 + wave;
    if (j >= N_NODES) return;
    int s = offs[j];
    int num = cnt[j];
    unsigned qoff = (unsigned)(q * 8);

    float acc[8];
    if (g == 0) {
        float d = dis[j];
        float dd = d * d;
        half8 mv = *(const half8*)(m + (((unsigned)j << 7) | qoff));
        #pragma unroll
        for (int i = 0; i < 8; i++) acc[i] = dd * (float)mv[i];
    } else {
        #pragma unroll
        for (int i = 0; i < 8; i++) acc[i] = 0.f;
    }

    for (int e = 0; e < num; e += 16) {
        float wv[4];
        unsigned off[4];
        #pragma unroll
        for (int k = 0; k < 4; k++) {
            int idx = e + k * 4 + g;
            int idc = (idx < num) ? idx : (num - 1);
            unsigned uu = csr[s + idc];
            wv[k] = (idx < num) ? wdec(uu) : 0.f;
            off[k] = ((uu & 0x1FFFFu) << 7) | qoff;
        }
        half8 r0 = *(const half8*)(m + off[0]);
        half8 r1 = *(const half8*)(m + off[1]);
        half8 r2 = *(const half8*)(m + off[2]);
        half8 r3 = *(const half8*)(m + off[3]);
        #pragma unroll
        for (int i = 0; i < 8; i++) acc[i] = fmaf(wv[0], (float)r0[i], acc[i]);
        #pragma unroll
        for (int i = 0; i < 8; i++) acc[i] = fmaf(wv[1], (float)r1[i], acc[i]);
        #pragma unroll
        for (int i = 0; i < 8; i++) acc[i] = fmaf(wv[2], (float)r2[i], acc[i]);
        #pragma unroll
        for (int i = 0; i < 8; i++) acc[i] = fmaf(wv[3], (float)r3[i], acc[i]);
    }

    #pragma unroll
    for (int i = 0; i < 8; i++) {
        acc[i] += __shfl_xor(acc[i], 16, 64);
        acc[i] += __shfl_xor(acc[i], 32, 64);
    }

    if (g == 0) {
        half8 o;
        #pragma unroll
        for (int i = 0; i < 8; i++) o[i] = (_Float16)acc[i];
        *(half8*)(out + (((unsigned)j << 7) | qoff)) = o;
    }
}

// ================= launch =================

extern "C" void kernel_launch(void* const* d_in, const int* in_sizes, int n_in,
                              void* d_out, int out_size, void* d_ws, size_t ws_size,
                              hipStream_t stream) {
    const float* x      = (const float*)d_in[0];
    const int*   ei     = (const int*)d_in[1];
    const float* ew     = (const float*)d_in[2];
    const float* enc_W1 = (const float*)d_in[3];
    const float* enc_b1 = (const float*)d_in[4];
    const float* enc_W2 = (const float*)d_in[5];
    const float* enc_b2 = (const float*)d_in[6];
    const float* c1_W   = (const float*)d_in[7];
    const float* c1_b   = (const float*)d_in[8];
    const float* c2_W   = (const float*)d_in[9];
    const float* c2_b   = (const float*)d_in[10];
    const float* dec_W1 = (const float*)d_in[11];
    const float* dec_b1 = (const float*)d_in[12];
    const float* dec_W2 = (const float*)d_in[13];
    const float* dec_b2 = (const float*)d_in[14];
    float* out = (float*)d_out;

    char* ws = (char*)d_ws;
    // CSR scratch aliases B1/B2 head (all dead before enc1/agg write them)
    unsigned long long* part   = (unsigned long long*)(ws);              // 14,413,824
    unsigned* Mcnt  = (unsigned*)(ws + 14413824);                        // 1,223,048
    unsigned* Mbase = (unsigned*)(ws + 15636872);                        // 1,223,048
    unsigned* btot  = (unsigned*)(ws + 16859920);                        // 1,564 (+pad)
    unsigned long long* sorted = (unsigned long long*)(ws + 16861488);   // 14,413,824
    _Float16* B1 = (_Float16*)(ws);                                      // 25,600,000
    _Float16* B2 = (_Float16*)(ws + 25600000);                           // 25,600,000
    _Float16* Wt = (_Float16*)(ws + 51200000);                           // 131,072
    float* dis  = (float*)(ws + 51331072);                               // 400,000
    int*   offs = (int*)  (ws + 51731072);                               // 400,000
    int*   cnt  = (int*)  (ws + 52131072);                               // 400,000
    unsigned* csr = (unsigned*)(ws + 52531072);                          // 7,206,912
    float* svec = (float*)(ws + 59737984);                               // 400,000
    float* bb   = (float*)(ws + 60137984);                               // 512
    // end ~60.1 MB

    k_count<<<NCHUNK, 256, 0, stream>>>(ei, Mcnt);
    k_base<<<NBKT, 256, 0, stream>>>(Mcnt, Mbase, btot);
    k_place<<<NCHUNK, 64, 0, stream>>>(ei, ew, Mbase, part);
    k_colsort<<<NBKT, 64, 0, stream>>>(btot, part, sorted, dis, offs, cnt);
    k_final<<<NBKT, 256, 0, stream>>>(sorted, dis, offs, cnt, csr, svec);

    prep_mm<<<64, 256, 0, stream>>>(enc_W2, c1_W, Wt);
    prep_bb<<<1, 128, 0, stream>>>(enc_b2, c1_W, bb);
    prep_tr<<<32, 256, 0, stream>>>(c2_W, dec_W1, Wt);
    enc1_kernel<<<(N_NODES + 255) / 256, 256, 0, stream>>>(x, enc_W1, enc_b1, B1);

    // conv1: agg(h1) -> gemm with Wc = enc_W2@c1_W, bias = s*bb + c1_b, relu
    agg_kernel<<<N_NODES / 4, 256, 0, stream>>>(B1, offs, cnt, csr, dis, B2);
    gemm_mfma<true, true, false, true><<<GEMM_GRID, 256, 0, stream>>>(
        B2, Wt + 0 * 16384, c1_b, B1, nullptr, nullptr, nullptr, svec, bb);
    // conv2: agg(o1) -> gemm c2_W + c2_b, relu
    agg_kernel<<<N_NODES / 4, 256, 0, stream>>>(B1, offs, cnt, csr, dis, B2);
    gemm_mfma<true, true, false, false><<<GEMM_GRID, 256, 0, stream>>>(
        B2, Wt + 1 * 16384, c2_b, B1, nullptr, nullptr, nullptr, nullptr, nullptr);
    // decoder: dec_W1 + b, relu; fused dec_W2 + softmax
    gemm_mfma<true, true, true, false><<<GEMM_GRID, 256, 0, stream>>>(
        B1, Wt + 2 * 16384, dec_b1, nullptr, dec_W2, dec_b2, out, nullptr, nullptr);
}